// Round 12
// baseline (768.272 us; speedup 1.0000x reference)
//
#include <hip/hip_runtime.h>
#include <hip/hip_bf16.h>
#include <math.h>

// ---------------- types ----------------
typedef __bf16 bf16x8 __attribute__((ext_vector_type(8)));
typedef __bf16 bf16x4 __attribute__((ext_vector_type(4)));
typedef float f32x4 __attribute__((ext_vector_type(4)));

__device__ __forceinline__ float gelu_fast(float v) {
    float z = v * (1.f + 0.044715f * v * v);
    return v / (1.f + __expf(-1.5957691216f * z));
}

// ---------------- conversion kernels ----------------
__global__ void cvt_f32_bf16(const float* __restrict__ in, __bf16* __restrict__ out, long n) {
    long i = ((long)blockIdx.x * 256 + threadIdx.x) * 4;
    long stride = (long)gridDim.x * 1024;
    for (; i < n; i += stride) {
        float4 v = *(const float4*)(in + i);
        out[i + 0] = (__bf16)v.x;
        out[i + 1] = (__bf16)v.y;
        out[i + 2] = (__bf16)v.z;
        out[i + 3] = (__bf16)v.w;
    }
}

// fused: x f32 [Z][rows][cols] -> xb bf16 (same layout) + xbT bf16 [Z][cols][rows]
__global__ void cvt_transpose(const float* __restrict__ in, __bf16* __restrict__ out,
                              __bf16* __restrict__ outT, int rows, int cols) {
    __shared__ __bf16 tile[32][33];
    in   += (long)blockIdx.z * rows * cols;
    out  += (long)blockIdx.z * rows * cols;
    outT += (long)blockIdx.z * rows * cols;
    int c0 = blockIdx.x * 32, r0 = blockIdx.y * 32;
    for (int i = threadIdx.y; i < 32; i += 8) {
        __bf16 v = (__bf16)in[(long)(r0 + i) * cols + c0 + threadIdx.x];
        tile[i][threadIdx.x] = v;
        out[(long)(r0 + i) * cols + c0 + threadIdx.x] = v;
    }
    __syncthreads();
    for (int i = threadIdx.y; i < 32; i += 8)
        outT[(long)(c0 + i) * rows + r0 + threadIdx.x] = tile[threadIdx.x][i];
}

// transpose + convert: in f32 [M][N] (ldin) -> out bf16 [N][M] (ldout), batched over z
__global__ void transpose_cvt(const float* __restrict__ in, __bf16* __restrict__ out,
                              int ldin, int ldout, long inBS, long outBS) {
    __shared__ __bf16 tile[32][33];
    in  += (long)blockIdx.z * inBS;
    out += (long)blockIdx.z * outBS;
    int n0 = blockIdx.x * 32, m0 = blockIdx.y * 32;
    for (int i = threadIdx.y; i < 32; i += 8)
        tile[i][threadIdx.x] = (__bf16)in[(long)(m0 + i) * ldin + n0 + threadIdx.x];
    __syncthreads();
    for (int i = threadIdx.y; i < 32; i += 8)
        out[(long)(n0 + i) * ldout + m0 + threadIdx.x] = tile[threadIdx.x][i];
}

// bf16 transpose: in [rows][cols] -> out [cols][rows], batched over z
__global__ void transpose_bf16(const __bf16* __restrict__ in, __bf16* __restrict__ out,
                               int rows, int cols) {
    __shared__ __bf16 tile[32][33];
    in  += (long)blockIdx.z * rows * cols;
    out += (long)blockIdx.z * rows * cols;
    int c0 = blockIdx.x * 32, r0 = blockIdx.y * 32;
    for (int i = threadIdx.y; i < 32; i += 8)
        tile[i][threadIdx.x] = in[(long)(r0 + i) * cols + c0 + threadIdx.x];
    __syncthreads();
    for (int i = threadIdx.y; i < 32; i += 8)
        out[(long)(c0 + i) * rows + r0 + threadIdx.x] = tile[threadIdx.x][i];
}

// ---------------- GEMM (proven structure + 8x8 patch swizzle) ----------------
// C[M,N] = A[M,K] @ Bt[N,K]^T (+epilogue). 128^2 tile, BK=64, 4 waves.
// launch_bounds min-waves raised to 4 blocks/CU (occupancy-hint experiment; VGPR 64
// leaves the register allocator unconstrained at this target).
template<bool ROWB, bool COLB, bool GELUF, bool RES, int OUT>
__global__ __launch_bounds__(256, 4) void gemm_bf16(
    const __bf16* __restrict__ A, int lda, long aBS,
    const __bf16* __restrict__ Bt, int ldb, long bBS,
    void* __restrict__ outp, int ldc, long cBS,
    const float* __restrict__ rowBias,
    const float* __restrict__ colBias,
    const __bf16* __restrict__ res, int ldres,
    int K)
{
    __shared__ __bf16 Asm[128 * 64];
    __shared__ __bf16 Bsm[128 * 64];
    const int tid = threadIdx.x;
    const int lane = tid & 63, wave = tid >> 6;
    const int wm = wave >> 1, wn = wave & 1;
    const int l15 = lane & 15, l4 = lane >> 4;

    // 8x8 patch per XCD (L2-resident panels); fallback 1D swizzle
    int bx = blockIdx.x, by = blockIdx.y;
    {
        int gx = gridDim.x, gy = gridDim.y;
        int nb = gx * gy;
        if ((gx & 7) == 0 && (gy & 7) == 0 && (nb & 511) == 0) {
            int id = by * gx + bx;
            int xcd = id & 7, local = id >> 3;
            int t = local >> 6, within = local & 63;
            int ppx = gx >> 3;
            int ppc = nb >> 9;
            int pid = xcd * ppc + t;
            int pgy = pid / ppx, pgx = pid % ppx;
            bx = pgx * 8 + (within & 7);
            by = pgy * 8 + (within >> 3);
        } else if ((nb & 7) == 0) {
            int id = by * gx + bx;
            int cpx = nb >> 3;
            int swz = (id & 7) * cpx + (id >> 3);
            bx = swz % gx;
            by = swz / gx;
        }
    }
    const long m0 = (long)bx * 128, n0 = (long)by * 128;
    A  += (long)blockIdx.z * aBS;
    Bt += (long)blockIdx.z * bBS;

    const int srow8 = lane >> 3;
    const int gunit = ((lane & 7) ^ srow8) << 3;
    const __bf16* Abase = A  + (m0 + wave * 8 + srow8) * (long)lda + gunit;
    const __bf16* Bbase = Bt + (n0 + wave * 8 + srow8) * (long)ldb + gunit;
    __bf16* AsmW = Asm + wave * 8 * 64;
    __bf16* BsmW = Bsm + wave * 8 * 64;
    const int swz_r = l15 & 7;

    f32x4 acc[4][4];
#pragma unroll
    for (int mi = 0; mi < 4; mi++)
#pragma unroll
        for (int ni = 0; ni < 4; ni++) acc[mi][ni] = (f32x4){0.f, 0.f, 0.f, 0.f};

    for (int k0 = 0; k0 < K; k0 += 64) {
        __syncthreads();
#pragma unroll
        for (int p = 0; p < 4; p++) {
            __builtin_amdgcn_global_load_lds(
                (const __attribute__((address_space(1))) unsigned int*)(Abase + (long)p * 32 * lda + k0),
                (__attribute__((address_space(3))) unsigned int*)(AsmW + p * 32 * 64), 16, 0, 0);
            __builtin_amdgcn_global_load_lds(
                (const __attribute__((address_space(1))) unsigned int*)(Bbase + (long)p * 32 * ldb + k0),
                (__attribute__((address_space(3))) unsigned int*)(BsmW + p * 32 * 64), 16, 0, 0);
        }
        asm volatile("s_waitcnt vmcnt(0)" ::: "memory");
        __syncthreads();
#pragma unroll
        for (int ks = 0; ks < 2; ks++) {
            bf16x8 af[4], bfv[4];
#pragma unroll
            for (int mi = 0; mi < 4; mi++)
                af[mi] = *(const bf16x8*)(Asm + (wm * 64 + mi * 16 + l15) * 64 + (((ks * 4 + l4) ^ swz_r) << 3));
#pragma unroll
            for (int ni = 0; ni < 4; ni++)
                bfv[ni] = *(const bf16x8*)(Bsm + (wn * 64 + ni * 16 + l15) * 64 + (((ks * 4 + l4) ^ swz_r) << 3));
#pragma unroll
            for (int mi = 0; mi < 4; mi++)
#pragma unroll
                for (int ni = 0; ni < 4; ni++)
                    acc[mi][ni] = __builtin_amdgcn_mfma_f32_16x16x32_bf16(af[mi], bfv[ni], acc[mi][ni], 0, 0, 0);
        }
    }

    float* outf = (float*)outp;
    __bf16* outb = (__bf16*)outp;
    const long cOff = (long)blockIdx.z * cBS;
#pragma unroll
    for (int mi = 0; mi < 4; mi++)
#pragma unroll
        for (int ni = 0; ni < 4; ni++) {
            long gmb = m0 + wm * 64 + mi * 16 + l4 * 4;
            long gc  = n0 + wn * 64 + ni * 16 + l15;
#pragma unroll
            for (int i = 0; i < 4; i++) {
                long gm = gmb + i;
                float v = acc[mi][ni][i];
                if (ROWB)  v += rowBias[gm];
                if (COLB)  v += colBias[gc];
                if (GELUF) v = gelu_fast(v);
                if (RES)   v += (float)res[gm * (long)ldres + gc];
                if (OUT == 0) outf[cOff + gm * (long)ldc + gc] = v;
                else          outb[cOff + gm * (long)ldc + gc] = (__bf16)v;
            }
        }
}

// ========== gemm128_split: 128x128 tile split-K, writes f32 partials ==========
__global__ __launch_bounds__(256, 4) void gemm128_split(
    const __bf16* __restrict__ A, int lda, long aBS,
    const __bf16* __restrict__ Bt, int ldb, long bBS,
    float* __restrict__ P, long cBS, int ldc,
    int Ksplit, int S)
{
    __shared__ __bf16 Asm[128 * 64];
    __shared__ __bf16 Bsm[128 * 64];
    const int tid = threadIdx.x;
    const int lane = tid & 63, wave = tid >> 6;
    const int wm = wave >> 1, wn = wave & 1;
    const int l15 = lane & 15, l4 = lane >> 4;
    const long m0 = (long)blockIdx.x * 128, n0 = (long)blockIdx.y * 128;
    const long zb = blockIdx.z / S;
    const int  sp = blockIdx.z % S;
    A  += zb * aBS + (long)sp * Ksplit;
    Bt += zb * bBS + (long)sp * Ksplit;

    const int srow8 = lane >> 3;
    const int gunit = ((lane & 7) ^ srow8) << 3;
    const __bf16* Abase = A + (m0 + wave * 8 + srow8) * (long)lda + gunit;
    const __bf16* Bbase = Bt + (n0 + wave * 8 + srow8) * (long)ldb + gunit;
    __bf16* AsmW = Asm + wave * 8 * 64;
    __bf16* BsmW = Bsm + wave * 8 * 64;
    const int swz_r = l15 & 7;

    f32x4 acc[4][4];
#pragma unroll
    for (int mi = 0; mi < 4; mi++)
#pragma unroll
        for (int ni = 0; ni < 4; ni++) acc[mi][ni] = (f32x4){0.f, 0.f, 0.f, 0.f};

    for (int k0 = 0; k0 < Ksplit; k0 += 64) {
        __syncthreads();
#pragma unroll
        for (int p = 0; p < 4; p++) {
            __builtin_amdgcn_global_load_lds(
                (const __attribute__((address_space(1))) unsigned int*)(Abase + (long)p * 32 * lda + k0),
                (__attribute__((address_space(3))) unsigned int*)(AsmW + p * 32 * 64), 16, 0, 0);
            __builtin_amdgcn_global_load_lds(
                (const __attribute__((address_space(1))) unsigned int*)(Bbase + (long)p * 32 * ldb + k0),
                (__attribute__((address_space(3))) unsigned int*)(BsmW + p * 32 * 64), 16, 0, 0);
        }
        asm volatile("s_waitcnt vmcnt(0)" ::: "memory");
        __syncthreads();
#pragma unroll
        for (int ks = 0; ks < 2; ks++) {
            bf16x8 af[4], bfv[4];
#pragma unroll
            for (int mi = 0; mi < 4; mi++)
                af[mi] = *(const bf16x8*)(Asm + (wm * 64 + mi * 16 + l15) * 64 + (((ks * 4 + l4) ^ swz_r) << 3));
#pragma unroll
            for (int ni = 0; ni < 4; ni++)
                bfv[ni] = *(const bf16x8*)(Bsm + (wn * 64 + ni * 16 + l15) * 64 + (((ks * 4 + l4) ^ swz_r) << 3));
#pragma unroll
            for (int mi = 0; mi < 4; mi++)
#pragma unroll
                for (int ni = 0; ni < 4; ni++)
                    acc[mi][ni] = __builtin_amdgcn_mfma_f32_16x16x32_bf16(af[mi], bfv[ni], acc[mi][ni], 0, 0, 0);
        }
    }

    float* out = P + (long)blockIdx.z * cBS;
#pragma unroll
    for (int mi = 0; mi < 4; mi++)
#pragma unroll
        for (int ni = 0; ni < 4; ni++) {
            long gmb = m0 + wm * 64 + mi * 16 + l4 * 4;
            long gc  = n0 + wn * 64 + ni * 16 + l15;
#pragma unroll
            for (int i = 0; i < 4; i++)
                out[(gmb + i) * (long)ldc + gc] = acc[mi][ni][i];
        }
}

// ---------- reduce S f32 partials -> bf16 (xp path) ----------
__global__ __launch_bounds__(256) void reduce_partials(
    const float* __restrict__ P, __bf16* __restrict__ out, int S, long total, long pBS)
{
    int b = blockIdx.z;
    long idx = ((long)blockIdx.x * 256 + threadIdx.x) * 4;
    if (idx >= total) return;
    const float* Pb = P + (long)b * S * pBS + idx;
    float4 a = *(const float4*)Pb;
    for (int s = 1; s < S; s++) {
        float4 v = *(const float4*)(Pb + (long)s * pBS);
        a.x += v.x; a.y += v.y; a.z += v.z; a.w += v.w;
    }
    __bf16* o = out + (long)b * total + idx;
    o[0] = (__bf16)a.x; o[1] = (__bf16)a.y; o[2] = (__bf16)a.z; o[3] = (__bf16)a.w;
}

// ---------- merged KV reduce: partials [S][256][2048] -> KP bf16 + VPt bf16 ----------
__global__ __launch_bounds__(256) void reduce_kv(
    const float* __restrict__ P, __bf16* __restrict__ KP, __bf16* __restrict__ VPt,
    const float* __restrict__ Eb, int S)
{
    int b = blockIdx.z;
    long idx = ((long)blockIdx.x * 256 + threadIdx.x) * 4;   // over 256*2048
    const float* Pb = P + (long)b * S * 524288 + idx;
    float4 a = *(const float4*)Pb;
    for (int s = 1; s < S; s++) {
        float4 v = *(const float4*)(Pb + (long)s * 524288);
        a.x += v.x; a.y += v.y; a.z += v.z; a.w += v.w;
    }
    int m = (int)(idx >> 11), n = (int)(idx & 2047);
    float bv = Eb[m];
    float av[4] = {a.x + bv, a.y + bv, a.z + bv, a.w + bv};
    if (n < 1024) {
        __bf16* o = KP + (long)b * 262144 + (long)m * 1024 + n;
        o[0] = (__bf16)av[0]; o[1] = (__bf16)av[1]; o[2] = (__bf16)av[2]; o[3] = (__bf16)av[3];
    } else {
        int c = n - 1024;
#pragma unroll
        for (int j = 0; j < 4; j++)
            VPt[(long)b * 262144 + (long)(c + j) * 256 + m] = (__bf16)av[j];
    }
}

// ---------------- fused Linformer attention ----------------
__global__ __launch_bounds__(256, 2) void attn_fused(
    const __bf16* __restrict__ Q, const __bf16* __restrict__ KP,
    const __bf16* __restrict__ VPt, __bf16* __restrict__ O)
{
    __shared__ __bf16 plds[4][4096];
    const int tid = threadIdx.x, lane = tid & 63, wave = tid >> 6;
    const int l15 = lane & 15, l4 = lane >> 4;
    const int h = blockIdx.y, b = blockIdx.z;
    const long row0 = (long)b * 4096 + (long)blockIdx.x * 64 + wave * 16;

    bf16x8 aq[2];
#pragma unroll
    for (int ks = 0; ks < 2; ks++)
        aq[ks] = *(const bf16x8*)(Q + (row0 + l15) * 1024 + h * 64 + ks * 32 + l4 * 8);

    f32x4 s[16];
#pragma unroll
    for (int f = 0; f < 16; f++) {
        f32x4 a = (f32x4){0.f, 0.f, 0.f, 0.f};
#pragma unroll
        for (int ks = 0; ks < 2; ks++) {
            bf16x8 bk = *(const bf16x8*)(KP + ((long)b * 256 + f * 16 + l15) * 1024 + h * 64 + ks * 32 + l4 * 8);
            a = __builtin_amdgcn_mfma_f32_16x16x32_bf16(aq[ks], bk, a, 0, 0, 0);
        }
        s[f] = a;
    }

    const float scale = 0.125f;
#pragma unroll
    for (int i = 0; i < 4; i++) {
        float m_ = -3.4e38f;
#pragma unroll
        for (int f = 0; f < 16; f++) { float v = s[f][i] * scale; s[f][i] = v; m_ = fmaxf(m_, v); }
#pragma unroll
        for (int msk = 1; msk < 16; msk <<= 1) m_ = fmaxf(m_, __shfl_xor(m_, msk));
        float su = 0.f;
#pragma unroll
        for (int f = 0; f < 16; f++) { float e = __expf(s[f][i] - m_); s[f][i] = e; su += e; }
#pragma unroll
        for (int msk = 1; msk < 16; msk <<= 1) su += __shfl_xor(su, msk);
        float inv = 1.f / su;
#pragma unroll
        for (int f = 0; f < 16; f++) s[f][i] *= inv;
    }

    __bf16* pl = plds[wave];
#pragma unroll
    for (int f = 0; f < 16; f++)
#pragma unroll
        for (int i = 0; i < 4; i++) {
            int r = l4 * 4 + i, c = f * 16 + l15;
            int off = r * 256 + ((((c >> 3) ^ (r & 7)) << 3) | (c & 7));
            pl[off] = (__bf16)s[f][i];
        }

    f32x4 o[4];
#pragma unroll
    for (int f2 = 0; f2 < 4; f2++) o[f2] = (f32x4){0.f, 0.f, 0.f, 0.f};
#pragma unroll
    for (int ks = 0; ks < 8; ks++) {
        int kk = ks * 32 + l4 * 8;
        int off = l15 * 256 + (((kk >> 3) ^ (l15 & 7)) << 3);
        bf16x8 ap = *(const bf16x8*)(pl + off);
#pragma unroll
        for (int f2 = 0; f2 < 4; f2++) {
            bf16x8 bv = *(const bf16x8*)(VPt + ((long)b * 1024 + h * 64 + f2 * 16 + l15) * 256 + kk);
            o[f2] = __builtin_amdgcn_mfma_f32_16x16x32_bf16(ap, bv, o[f2], 0, 0, 0);
        }
    }
#pragma unroll
    for (int f2 = 0; f2 < 4; f2++)
#pragma unroll
        for (int i = 0; i < 4; i++)
            O[(row0 + l4 * 4 + i) * 1024 + h * 64 + f2 * 16 + l15] = (__bf16)o[f2][i];
}

// ---------------- LayerNorm (row=1024), bf16 in; writes xb (+xout if WF32) ----------------
template<bool WF32>
__global__ __launch_bounds__(256) void ln_kernel(const __bf16* __restrict__ y,
    const float* __restrict__ g, const float* __restrict__ b,
    float* __restrict__ xout, __bf16* __restrict__ xb)
{
    const int row = blockIdx.x;
    const int t = threadIdx.x;
    bf16x4 yv = *(const bf16x4*)(y + (long)row * 1024 + t * 4);
    float v0 = (float)yv[0], v1 = (float)yv[1], v2 = (float)yv[2], v3 = (float)yv[3];
    float s  = v0 + v1 + v2 + v3;
    float ss = v0 * v0 + v1 * v1 + v2 * v2 + v3 * v3;
#pragma unroll
    for (int m = 1; m < 64; m <<= 1) { s += __shfl_xor(s, m); ss += __shfl_xor(ss, m); }
    __shared__ float red[2][4];
    const int wave = t >> 6, lane = t & 63;
    if (lane == 0) { red[0][wave] = s; red[1][wave] = ss; }
    __syncthreads();
    s  = red[0][0] + red[0][1] + red[0][2] + red[0][3];
    ss = red[1][0] + red[1][1] + red[1][2] + red[1][3];
    const float mu = s * (1.f / 1024.f);
    const float var = ss * (1.f / 1024.f) - mu * mu;
    const float rs = rsqrtf(var + 1e-5f);
    const float4 gv = ((const float4*)g)[t];
    const float4 bv = ((const float4*)b)[t];
    float o0 = (v0 - mu) * rs * gv.x + bv.x;
    float o1 = (v1 - mu) * rs * gv.y + bv.y;
    float o2 = (v2 - mu) * rs * gv.z + bv.z;
    float o3 = (v3 - mu) * rs * gv.w + bv.w;
    if (WF32) {
        float4 ov; ov.x = o0; ov.y = o1; ov.z = o2; ov.w = o3;
        ((float4*)(xout + (long)row * 1024))[t] = ov;
    }
    __bf16* xr = xb + (long)row * 1024 + t * 4;
    xr[0] = (__bf16)o0; xr[1] = (__bf16)o1; xr[2] = (__bf16)o2; xr[3] = (__bf16)o3;
}

// ---------------- host launch ----------------
extern "C" void kernel_launch(void* const* d_in, const int* in_sizes, int n_in,
                              void* d_out, int out_size, void* d_ws, size_t ws_size,
                              hipStream_t stream) {
    const float* x   = (const float*)d_in[0];
    const float* Wq  = (const float*)d_in[1];
    const float* Wk  = (const float*)d_in[2];
    const float* Wv  = (const float*)d_in[3];
    const float* Wo  = (const float*)d_in[4];
    const float* bo  = (const float*)d_in[5];
    const float* Ew  = (const float*)d_in[6];
    const float* Eb  = (const float*)d_in[7];
    const float* W1  = (const float*)d_in[8];
    const float* b1  = (const float*)d_in[9];
    const float* W2  = (const float*)d_in[10];
    const float* b2  = (const float*)d_in[11];
    const float* lng = (const float*)d_in[12];
    const float* lnb = (const float*)d_in[13];
    float* xout = (float*)d_out;

    char* base = (char*)d_ws;
    size_t off = 0;
    auto alloc = [&](size_t bytes) { void* p = base + off; off += (bytes + 255) & ~(size_t)255; return p; };
    __bf16* Wqt  = (__bf16*)alloc(2ll * 1024 * 1024 * 2);
    __bf16* WkVt = (__bf16*)alloc(2ll * 2048 * 1024 * 2);
    __bf16* Wot  = (__bf16*)alloc(2ll * 1024 * 1024 * 2);
    __bf16* W1t  = (__bf16*)alloc(2ll * 1024 * 4096 * 2);
    __bf16* W2t  = (__bf16*)alloc(2ll * 1024 * 4096 * 2);
    __bf16* Ewb  = (__bf16*)alloc(256ll * 4096 * 2);
    __bf16* xb   = (__bf16*)alloc(8192ll * 1024 * 2);
    __bf16* xbT  = (__bf16*)alloc(2ll * 1024 * 4096 * 2);
    __bf16* ybf  = (__bf16*)alloc(8192ll * 1024 * 2);
    __bf16* xp   = (__bf16*)alloc(2ll * 256 * 1024 * 2);
    __bf16* KPb  = (__bf16*)alloc(2ll * 256 * 1024 * 2);
    __bf16* VPt  = (__bf16*)alloc(2ll * 1024 * 256 * 2);
    __bf16* big  = (__bf16*)alloc(8192ll * 4096 * 2);   // 64 MB scratch region
    float*  xpP  = (float*)big;                          // [16][256*1024] f32 = 16MB
    float*  kvP  = (float*)((char*)big + (16ll << 20));  // [8][256*2048]  f32 = 16MB
    __bf16* Qb   = big;                                  // [8192][1024] (over xpP, dead)
    __bf16* Ob   = big + (32ll << 20);                   // [8192][1024] at +32MB
    __bf16* hbuf = big;                                  // [8192][4096] (FF stage)

    // fused: xb + xbT (layer-0 input) in one pass over x
    cvt_transpose<<<dim3(32, 128, 2), dim3(32, 8), 0, stream>>>(x, xb, xbT, 4096, 1024);
    cvt_f32_bf16<<<1024, 256, 0, stream>>>(Ew, Ewb, 1048576);
    transpose_cvt<<<dim3(2, 32, 32),  dim3(32, 8), 0, stream>>>(Wq, Wqt, 64, 1024, 65536, 65536);
    transpose_cvt<<<dim3(2, 32, 16),  dim3(32, 8), 0, stream>>>(Wk,           WkVt,                     64, 1024, 65536, 65536);
    transpose_cvt<<<dim3(2, 32, 16),  dim3(32, 8), 0, stream>>>(Wk + 1048576, WkVt + 2097152,           64, 1024, 65536, 65536);
    transpose_cvt<<<dim3(2, 32, 16),  dim3(32, 8), 0, stream>>>(Wv,           WkVt + 1048576,           64, 1024, 65536, 65536);
    transpose_cvt<<<dim3(2, 32, 16),  dim3(32, 8), 0, stream>>>(Wv + 1048576, WkVt + 2097152 + 1048576, 64, 1024, 65536, 65536);
    transpose_cvt<<<dim3(32, 32, 2),  dim3(32, 8), 0, stream>>>(Wo, Wot, 1024, 1024, 1048576, 1048576);
    transpose_cvt<<<dim3(128, 32, 2), dim3(32, 8), 0, stream>>>(W1, W1t, 4096, 1024, 4194304, 4194304);
    transpose_cvt<<<dim3(32, 128, 2), dim3(32, 8), 0, stream>>>(W2, W2t, 1024, 4096, 4194304, 4194304);

    for (int l = 0; l < 2; l++) {
        const __bf16* Wqt_l  = Wqt  + (long)l * 1048576;
        const __bf16* WkVt_l = WkVt + (long)l * 2097152;
        const __bf16* Wot_l  = Wot  + (long)l * 1048576;
        const __bf16* W1t_l  = W1t  + (long)l * 4194304;
        const __bf16* W2t_l  = W2t  + (long)l * 4194304;

        // xbT = xb^T (layer 0 got it fused with the f32 conversion)
        if (l > 0)
            transpose_bf16<<<dim3(32, 128, 2), dim3(32, 8), 0, stream>>>(xb, xbT, 4096, 1024);
        // xp = Ew @ x  (split-K 8)
        gemm128_split<<<dim3(2, 8, 16), 256, 0, stream>>>(
            Ewb, 4096, 0, xbT, 4096, 4194304, xpP, 262144, 1024, 512, 8);
        reduce_partials<<<dim3(256, 1, 2), 256, 0, stream>>>(xpP, xp, 8, 262144, 262144);
        // [KP|VP] = xp @ [Wk|Wv]^T + Eb  (merged, split-K 4)
        gemm128_split<<<dim3(2, 16, 8), 256, 0, stream>>>(
            xp, 1024, 262144, WkVt_l, 1024, 0, kvP, 524288, 2048, 256, 4);
        reduce_kv<<<dim3(512, 1, 2), 256, 0, stream>>>(kvP, KPb, VPt, Eb, 4);
        // Q = xb @ Wq^T
        gemm_bf16<false, false, false, false, 1><<<dim3(64, 8, 1), 256, 0, stream>>>(
            xb, 1024, 0, Wqt_l, 1024, 0, (void*)Qb, 1024, 0, nullptr, nullptr, nullptr, 0, 1024);
        // attention
        attn_fused<<<dim3(64, 16, 2), 256, 0, stream>>>(Qb, KPb, VPt, Ob);
        // attn_out = O @ Wo^T + bo + residual(xb) -> ybf
        gemm_bf16<false, true, false, true, 1><<<dim3(64, 8, 1), 256, 0, stream>>>(
            Ob, 1024, 0, Wot_l, 1024, 0, (void*)ybf, 1024, 0,
            nullptr, bo + l * 1024, xb, 1024, 1024);
        ln_kernel<false><<<8192, 256, 0, stream>>>(ybf, lng + (2 * l + 0) * 1024, lnb + (2 * l + 0) * 1024, nullptr, xb);
        // h = gelu(x @ W1 + b1)
        gemm_bf16<false, true, true, false, 1><<<dim3(64, 32, 1), 256, 0, stream>>>(
            xb, 1024, 0, W1t_l, 1024, 0, (void*)hbuf, 4096, 0,
            nullptr, b1 + l * 4096, nullptr, 0, 1024);
        // ff = h @ W2 + b2 + residual(xb) -> ybf
        gemm_bf16<false, true, false, true, 1><<<dim3(64, 8, 1), 256, 0, stream>>>(
            hbuf, 4096, 0, W2t_l, 4096, 0, (void*)ybf, 1024, 0,
            nullptr, b2 + l * 1024, xb, 1024, 4096);
        if (l == 1)
            ln_kernel<true><<<8192, 256, 0, stream>>>(ybf, lng + 3 * 1024, lnb + 3 * 1024, xout, xb);
        else
            ln_kernel<false><<<8192, 256, 0, stream>>>(ybf, lng + 1 * 1024, lnb + 1 * 1024, nullptr, xb);
    }
}